// Round 5
// baseline (555.412 us; speedup 1.0000x reference)
//
#include <hip/hip_runtime.h>
#include <math.h>

#define KD     768     // embedding dim (elements = bytes in fp8)
#define MT     64      // M tile (queries) per block (4-wave blocks)
#define NT     128     // N tile (bank rows)
#define KB     128     // K bytes per mfma_scale (K=128)
#define NKC    6       // K chunks per tile (768/128)
#define NSPLIT 32      // bank splits per M tile
#define BIGF   3.0e38f

typedef __attribute__((ext_vector_type(4))) int   i32x4;
typedef __attribute__((ext_vector_type(8))) int   i32x8;
typedef __attribute__((ext_vector_type(4))) float f32x4;

// ---- software RNE float -> OCP e4m3fn (data ~N(0,1); saturation irrelevant)
__device__ __forceinline__ unsigned f2e4m3(float x) {
    unsigned u = __float_as_uint(x);
    unsigned s = (u >> 24) & 0x80u;
    float ax = __uint_as_float(u & 0x7fffffffu);
    if (ax < 0.015625f) {                       // subnormal region: step 2^-9
        int n = (int)rintf(ax * 512.0f);        // RNE, n in [0,8]
        if (n >= 8) return s | 0x08u;
        return s | (unsigned)n;
    }
    if (ax >= 464.0f) return s | 0x7Eu;         // saturate to 448
    unsigned m = __float_as_uint(ax);
    unsigned low = m & 0xFFFFFu;
    unsigned r = m >> 20;
    r += (low > 0x80000u) || (low == 0x80000u && (r & 1u));
    int ef = (int)(r >> 3) - 120;               // -127 + 7 (carry-safe)
    return s | ((unsigned)ef << 3) | (r & 7u);
}

__device__ __forceinline__ void ins3(float* t, float v) {
    float lo0 = fminf(t[0], v);
    float hi0 = fmaxf(t[0], v);
    float lo1 = fminf(t[1], hi0);
    float hi1 = fmaxf(t[1], hi0);
    float lo2 = fminf(t[2], hi1);
    t[0] = lo0; t[1] = lo1; t[2] = lo2;
}
__device__ __forceinline__ void async16(unsigned char* lds, const unsigned char* g) {
    __builtin_amdgcn_global_load_lds(
        (const __attribute__((address_space(1))) unsigned int*)g,
        (__attribute__((address_space(3))) unsigned int*)lds, 16, 0, 0);
}

// ---- emb [B][768][1024] -> qf8 [B*1024][768] e4m3 + q2 partials (atomicAdd) ----
// grid = B * 16 hw-tiles * 12 e-groups (64 e each) = 1536 blocks (was 384:
// 1.5 blocks/CU + serial 4-deep e-loop -> latency-bound; now 6/CU).
__global__ void q_prep_k(const float* __restrict__ emb, unsigned char* __restrict__ qf8,
                         float* __restrict__ q2) {
    __shared__ float s[64][65];
    int bx  = blockIdx.x;
    int b   = bx / 192;
    int rem = bx % 192;
    int hw0 = (rem & 15) * 64;
    int eg  = rem >> 4;                           // 0..11
    int e0  = eg * 64;
    const float* src = emb + (size_t)b * KD * 1024;
    unsigned int* q4 = (unsigned int*)qf8;
    #pragma unroll
    for (int i = 0; i < 16; ++i) {
        int idx = threadIdx.x + i * 256;          // 0..4095
        int ee = idx >> 6, hh = idx & 63;
        s[ee][hh] = src[(size_t)(e0 + ee) * 1024 + hw0 + hh];
    }
    __syncthreads();
    #pragma unroll
    for (int i = 0; i < 4; ++i) {
        int slot = threadIdx.x + i * 256;         // 0..1023 : (qq, e4)
        int qq = slot >> 4, e4 = slot & 15;
        float v0 = s[e4 * 4 + 0][qq], v1 = s[e4 * 4 + 1][qq];
        float v2 = s[e4 * 4 + 2][qq], v3 = s[e4 * 4 + 3][qq];
        unsigned p = f2e4m3(v0) | (f2e4m3(v1) << 8)
                   | (f2e4m3(v2) << 16) | (f2e4m3(v3) << 24);
        q4[((size_t)b * 1024 + hw0 + qq) * (KD / 4) + e0 / 4 + e4] = p;
        float part = 0.f;
        part = fmaf(v0, v0, part); part = fmaf(v1, v1, part);
        part = fmaf(v2, v2, part); part = fmaf(v3, v3, part);
        #pragma unroll
        for (int off = 1; off < 16; off <<= 1) part += __shfl_xor(part, off, 64);
        if ((threadIdx.x & 15) == 0) atomicAdd(&q2[b * 1024 + hw0 + qq], part);
    }
}

// ---- bank -> bf8 e4m3 (zero-padded) + exact fp32 b2 norms (BIGF pad) ----
__global__ void bank_prep_k(const float* __restrict__ bank, unsigned char* __restrict__ bf8,
                            float* __restrict__ b2, int N, int Npad) {
    int gid = blockIdx.x * 256 + threadIdx.x;
    int row = gid >> 6, lane = gid & 63;
    if (row >= Npad) return;
    unsigned int* b4 = (unsigned int*)bf8;
    if (row < N) {
        const float4* src = (const float4*)(bank + (size_t)row * KD);
        float s = 0.f;
        #pragma unroll
        for (int i = 0; i < KD / 256; ++i) {
            float4 v = src[lane + i * 64];
            s = fmaf(v.x, v.x, s); s = fmaf(v.y, v.y, s);
            s = fmaf(v.z, v.z, s); s = fmaf(v.w, v.w, s);
            unsigned p = f2e4m3(v.x) | (f2e4m3(v.y) << 8)
                       | (f2e4m3(v.z) << 16) | (f2e4m3(v.w) << 24);
            b4[(size_t)row * (KD / 4) + lane + i * 64] = p;
        }
        #pragma unroll
        for (int off = 32; off; off >>= 1) s += __shfl_down(s, off, 64);
        if (lane == 0) b2[row] = s;
    } else {
        #pragma unroll
        for (int i = 0; i < KD / 256; ++i) b4[(size_t)row * (KD / 4) + lane + i * 64] = 0;
        if (lane == 0) b2[row] = BIGF;
    }
}

// ---- stage one 16 KB B K-chunk (128 rows x 128 B), XOR-swizzled on global src ----
// LDS dest lane-linear (DMA requirement); swizzle pre-applied to global address.
// 256 threads: 4 x async16 each (4 VMEM ops per thread per stage).
__device__ __forceinline__ void stage_b(unsigned char* buf, const unsigned char* gB,
                                        int k0, int tid) {
    #pragma unroll
    for (int i = 0; i < 4; ++i) {                 // 1024 slots of 16 B
        int s = tid + i * 256;
        int m = s >> 3, g = s & 7;
        int G = g ^ (m & 7);
        async16(buf + s * 16, gB + (size_t)m * KD + k0 + G * 16);
    }
}

__device__ __forceinline__ i32x8 frag_read(const unsigned char* st, int base, int o0, int o1) {
    i32x4 lo = *(const i32x4*)&st[base + o0];
    i32x4 hi = *(const i32x4*)&st[base + o1];
    return __builtin_shufflevector(lo, hi, 0, 1, 2, 3, 4, 5, 6, 7);
}

// ---- main: fp8 MFMA distance GEMM + fused top-3 ----
// Evidence (R0..R4): win condition = R3's traffic plan (A in regs, B-only
// LDS: 74us of bank time/CU) at >=3 waves/SIMD. R3's footprint (116 VGPR +
// 32 AGPR ~ 148) FITS 3 waves/SIMD (cap 170) but its 8-wave block is a
// monolith (1.5 blocks can't be resident). Fix: 4-wave (256-thr) block,
// tile 64x128, SAME per-wave plan (wave 32x64, mi=2 ni=4, af[6][2]=96).
// __launch_bounds__(256,3) -> 3 blocks/CU = 12 waves, 3/SIMD.
// LDS/block: 3x16KB B-ring + b2s = 51.7 KB; x3 = 155 KB <= 160 KB.
// Pipeline (proven R3/R4): depth-2 DMA prefetch, counted vmcnt(4), one raw
// s_barrier per kc, VMEM-free main loop (b2 cached in LDS prologue).
// grid = 4096 = 128 mt x 32 sp; 16 mts per XCD -> A hot 768 KB/XCD in L2,
// B stream of each sp shared by 16 mt-blocks on that XCD.
__global__ __launch_bounds__(256, 3)
void knn_mfma_k(const unsigned char* __restrict__ qf8, const unsigned char* __restrict__ bf8,
                const float* __restrict__ b2g, float* __restrict__ cand,
                int ntiles, int Q) {
    __shared__ unsigned char bst[3][NT * KB];     // 3 x 16 KB B chunk ring
    __shared__ float b2s[5 * NT];                 // numnt <= 5 b2 tiles

    const int tid  = threadIdx.x;
    const int lane = tid & 63;
    const int quad = lane >> 4;
    const int l15  = lane & 15;
    const int wid  = tid >> 6;                    // 0..3
    const int wm   = wid & 1;                     // M half (32 rows)
    const int wn   = wid >> 1;                    // N half (64 cols)
    const int xr   = l15 & 7;

    const int bx   = blockIdx.x;
    const int xcd  = bx & 7;
    const int rr_  = bx >> 9;                     // temporal round 0..7
    const int jj   = (bx >> 3) & 63;
    const int mt   = xcd * 16 + (jj & 15);        // 0..127, 16 mts per XCD
    const int sp   = (jj >> 4) + 4 * rr_;         // 0..31
    const int Mbase = mt * MT;

    const int numnt = (ntiles - sp + NSPLIT - 1) / NSPLIT; // 4 or 5

    // prologue: b2 for this block's N tiles -> LDS (keeps main loop VMEM-free)
    for (int idx = tid; idx < numnt * NT; idx += 256) {
        int slot = idx >> 7, col = idx & 127;
        b2s[idx] = b2g[(size_t)(sp + slot * NSPLIT) * NT + col];
    }

    // prologue: A (this wave's 32 rows, full K=768) -> registers.
    // 16x16x128 A layout: row = l15, K bytes = quad*32 + [0,32).
    const unsigned char* gA = qf8 + ((size_t)Mbase + 32 * wm + l15) * KD + quad * 32;
    i32x8 af[NKC][2];
    #pragma unroll
    for (int kc = 0; kc < NKC; ++kc)
        #pragma unroll
        for (int mi = 0; mi < 2; ++mi) {
            const i32x4* p = (const i32x4*)(gA + (size_t)mi * 16 * KD + kc * KB);
            i32x4 lo = p[0];
            i32x4 hi = p[1];
            af[kc][mi] = __builtin_shufflevector(lo, hi, 0, 1, 2, 3, 4, 5, 6, 7);
        }

    float top3[24];
    #pragma unroll
    for (int i = 0; i < 24; ++i) top3[i] = BIGF;
    f32x4 acc[2][4];
    #pragma unroll
    for (int a = 0; a < 2; ++a)
        #pragma unroll
        for (int b = 0; b < 4; ++b) acc[a][b] = (f32x4){0.f, 0.f, 0.f, 0.f};

    const int o0 = ((2 * quad) ^ xr) * 16;
    const int o1 = ((2 * quad + 1) ^ xr) * 16;
    int bb[4];
    #pragma unroll
    for (int ni = 0; ni < 4; ++ni) bb[ni] = (64 * wn + 16 * ni + l15) * KB;

    __syncthreads();                              // drains all prologue mem ops

    // depth-2 prefetch: chunks 0,1 of first tile in flight (8 DMAs/thread)
    const unsigned char* gB0 = bf8 + (size_t)sp * NT * KD;
    stage_b(bst[0], gB0, 0, tid);
    stage_b(bst[1], gB0, KB, tid);

    for (int i = 0; i < numnt; ++i) {
        const unsigned char* gBc = bf8 + (size_t)(sp + i * NSPLIT) * NT * KD;
        const bool last = (i == numnt - 1);
        const unsigned char* gBn = last ? gBc
                                 : bf8 + (size_t)(sp + (i + 1) * NSPLIT) * NT * KD;
        #pragma unroll
        for (int kc = 0; kc < NKC; ++kc) {
            // invariant: chunks c, c+1 outstanding (4 DMAs each per thread)
            if (last && kc == NKC - 1) asm volatile("s_waitcnt vmcnt(0)" ::: "memory");
            else                       asm volatile("s_waitcnt vmcnt(4)" ::: "memory");
            __builtin_amdgcn_s_barrier();         // chunk c visible to all waves
            if (!(last && kc >= NKC - 2)) {       // issue chunk c+2
                if (kc < NKC - 2) stage_b(bst[(kc + 2) % 3], gBc, (kc + 2) * KB, tid);
                else              stage_b(bst[(kc + 2) % 3], gBn, (kc - 4) * KB, tid);
            }
            const unsigned char* st = bst[kc % 3];
            #pragma unroll
            for (int ni = 0; ni < 4; ++ni) {
                i32x8 bfr = frag_read(st, bb[ni], o0, o1);
                #pragma unroll
                for (int mi = 0; mi < 2; ++mi)
                    acc[mi][ni] = __builtin_amdgcn_mfma_scale_f32_16x16x128_f8f6f4(
                        af[kc][mi], bfr, acc[mi][ni], 0, 0,   // fp8 x fp8
                        0, 127, 0, 127);                      // identity E8M0 scales
            }
        }
        // epilogue: s = b2 - 2*dot (q2 added in scores_k; per-row const
        // preserves order). Overlaps the in-flight prefetch DMAs.
        const float* b2p = &b2s[i * NT + 64 * wn];
        #pragma unroll
        for (int ni = 0; ni < 4; ++ni) {
            float b2v = b2p[16 * ni + l15];
            #pragma unroll
            for (int mi = 0; mi < 2; ++mi)
                #pragma unroll
                for (int r = 0; r < 4; ++r) {
                    float s = fmaf(-2.0f, acc[mi][ni][r], b2v);
                    ins3(&top3[(mi * 4 + r) * 3], s);
                }
        }
        #pragma unroll
        for (int a = 0; a < 2; ++a)
            #pragma unroll
            for (int b = 0; b < 4; ++b) acc[a][b] = (f32x4){0.f, 0.f, 0.f, 0.f};
    }

    // merge the 16 column-partials per query row via shfl_xor butterfly
    #pragma unroll
    for (int mi = 0; mi < 2; ++mi)
        #pragma unroll
        for (int r = 0; r < 4; ++r) {
            float a0 = top3[(mi * 4 + r) * 3 + 0];
            float a1 = top3[(mi * 4 + r) * 3 + 1];
            float a2 = top3[(mi * 4 + r) * 3 + 2];
            #pragma unroll
            for (int off = 1; off < 16; off <<= 1) {
                float b0 = __shfl_xor(a0, off, 64);
                float b1 = __shfl_xor(a1, off, 64);
                float b2x = __shfl_xor(a2, off, 64);
                float t[3] = {a0, a1, a2};
                ins3(t, b0); ins3(t, b1); ins3(t, b2x);
                a0 = t[0]; a1 = t[1]; a2 = t[2];
            }
            if (l15 == 0) {
                int row = Mbase + 32 * wm + 16 * mi + 4 * quad + r;
                float* o = cand + ((size_t)(sp * 2 + wn) * Q + row) * 3;
                o[0] = a0; o[1] = a1; o[2] = a2;
            }
        }
}

// ---- merge 64 split-partials: one WAVE per query, lane = partial ----
__global__ void scores_k(const float* __restrict__ cand, const float* __restrict__ q2g,
                         float* __restrict__ scores, int Q) {
    int gid  = blockIdx.x * 256 + threadIdx.x;
    int q    = gid >> 6;
    int lane = gid & 63;
    if (q >= Q) return;
    const float* c = cand + ((size_t)lane * Q + q) * 3;
    float a0 = c[0], a1 = c[1], a2 = c[2];
    #pragma unroll
    for (int off = 1; off < 64; off <<= 1) {
        float b0 = __shfl_xor(a0, off, 64);
        float b1 = __shfl_xor(a1, off, 64);
        float b2x = __shfl_xor(a2, off, 64);
        float t[3] = {a0, a1, a2};
        ins3(t, b0); ins3(t, b1); ins3(t, b2x);
        a0 = t[0]; a1 = t[1]; a2 = t[2];
    }
    if (lane == 0) {
        float q2 = q2g[q];
        float s = (sqrtf(fmaxf(q2 + a0, 1e-12f)) +
                   sqrtf(fmaxf(q2 + a1, 1e-12f)) +
                   sqrtf(fmaxf(q2 + a2, 1e-12f))) * (1.f / 3.f);
        scores[q] = s;
    }
}

// ---- bilinear x16 upsample, half-pixel, edge clamp ----
__global__ void upsample_k(const float* __restrict__ scores, float* __restrict__ out, int total) {
    int idx = blockIdx.x * blockDim.x + threadIdx.x;
    if (idx >= total) return;
    int x = idx & 511;
    int y = (idx >> 9) & 511;
    int b = idx >> 18;
    float sx = (x + 0.5f) * (1.f / 16.f) - 0.5f;
    float sy = (y + 0.5f) * (1.f / 16.f) - 0.5f;
    int x0 = (int)floorf(sx);
    int y0 = (int)floorf(sy);
    float wx = sx - (float)x0;
    float wy = sy - (float)y0;
    int x0c = min(max(x0, 0), 31), x1c = min(max(x0 + 1, 0), 31);
    int y0c = min(max(y0, 0), 31), y1c = min(max(y0 + 1, 0), 31);
    const float* sb = scores + (size_t)b * 1024;
    float v00 = sb[y0c * 32 + x0c], v01 = sb[y0c * 32 + x1c];
    float v10 = sb[y1c * 32 + x0c], v11 = sb[y1c * 32 + x1c];
    float v0 = v00 + wx * (v01 - v00);
    float v1 = v10 + wx * (v11 - v10);
    out[idx] = v0 + wy * (v1 - v0);
}

extern "C" void kernel_launch(void* const* d_in, const int* in_sizes, int n_in,
                              void* d_out, int out_size, void* d_ws, size_t ws_size,
                              hipStream_t stream) {
    const float* emb  = (const float*)d_in[0];
    const float* bank = (const float*)d_in[1];
    const int Q      = in_sizes[0] / KD;             // 8192
    const int B      = Q / 1024;                     // 8
    const int Nbank  = in_sizes[1] / KD;             // 20000
    const int ntiles = (Nbank + NT - 1) / NT;        // 157
    const int Npad   = ntiles * NT;                  // 20096
    const int Mtiles = Q / MT;                       // 128

    // workspace layout
    unsigned char* qf8 = (unsigned char*)d_ws;                         // Q*KD bytes
    unsigned char* bf8 = qf8 + (size_t)Q * KD;                         // Npad*KD bytes
    float* fbase  = (float*)(bf8 + (size_t)Npad * KD);
    float* q2     = fbase;                                             // Q
    float* b2     = q2 + Q;                                            // Npad
    float* cand   = b2 + Npad;                                         // NSPLIT*2*Q*3
    float* scores = cand + (size_t)NSPLIT * 2 * Q * 3;                 // Q
    float* out    = (float*)d_out;

    hipMemsetAsync(q2, 0, Q * sizeof(float), stream);  // q2 accumulated via atomicAdd
    hipLaunchKernelGGL(q_prep_k, dim3(B * 192), dim3(256), 0, stream, emb, qf8, q2);
    hipLaunchKernelGGL(bank_prep_k, dim3((Npad * 64 + 255) / 256), dim3(256), 0, stream,
                       bank, bf8, b2, Nbank, Npad);
    hipLaunchKernelGGL(knn_mfma_k, dim3(Mtiles * NSPLIT), dim3(256), 0, stream,
                       qf8, bf8, b2, cand, ntiles, Q);
    hipLaunchKernelGGL(scores_k, dim3((Q * 64 + 255) / 256), dim3(256), 0, stream,
                       cand, q2, scores, Q);
    hipLaunchKernelGGL(upsample_k, dim3((out_size + 255) / 256), dim3(256), 0, stream,
                       scores, out, out_size);
}

// Round 6
// 341.342 us; speedup vs baseline: 1.6271x; 1.6271x over previous
//
#include <hip/hip_runtime.h>
#include <math.h>

#define KD     768     // embedding dim (elements = bytes in fp8)
#define MT     64      // M tile (queries) per block (4-wave blocks)
#define NT     128     // N tile (bank rows)
#define KB     128     // K bytes per mfma_scale (K=128)
#define NKC    6       // K chunks per tile (768/128)
#define NSPLIT 32      // bank splits per M tile
#define BIGF   3.0e38f

typedef __attribute__((ext_vector_type(4))) int   i32x4;
typedef __attribute__((ext_vector_type(8))) int   i32x8;
typedef __attribute__((ext_vector_type(4))) float f32x4;

// ---- software RNE float -> OCP e4m3fn (data ~N(0,1); saturation irrelevant)
__device__ __forceinline__ unsigned f2e4m3(float x) {
    unsigned u = __float_as_uint(x);
    unsigned s = (u >> 24) & 0x80u;
    float ax = __uint_as_float(u & 0x7fffffffu);
    if (ax < 0.015625f) {                       // subnormal region: step 2^-9
        int n = (int)rintf(ax * 512.0f);        // RNE, n in [0,8]
        if (n >= 8) return s | 0x08u;
        return s | (unsigned)n;
    }
    if (ax >= 464.0f) return s | 0x7Eu;         // saturate to 448
    unsigned m = __float_as_uint(ax);
    unsigned low = m & 0xFFFFFu;
    unsigned r = m >> 20;
    r += (low > 0x80000u) || (low == 0x80000u && (r & 1u));
    int ef = (int)(r >> 3) - 120;               // -127 + 7 (carry-safe)
    return s | ((unsigned)ef << 3) | (r & 7u);
}

__device__ __forceinline__ void ins3(float* t, float v) {
    float lo0 = fminf(t[0], v);
    float hi0 = fmaxf(t[0], v);
    float lo1 = fminf(t[1], hi0);
    float hi1 = fmaxf(t[1], hi0);
    float lo2 = fminf(t[2], hi1);
    t[0] = lo0; t[1] = lo1; t[2] = lo2;
}
__device__ __forceinline__ void async16(unsigned char* lds, const unsigned char* g) {
    __builtin_amdgcn_global_load_lds(
        (const __attribute__((address_space(1))) unsigned int*)g,
        (__attribute__((address_space(3))) unsigned int*)lds, 16, 0, 0);
}

// ---- emb [B][768][1024] -> qf8 [B*1024][768] e4m3 + q2 partials (atomicAdd) ----
// grid = B * 16 hw-tiles * 12 e-groups (64 e each) = 1536 blocks (6/CU).
__global__ void q_prep_k(const float* __restrict__ emb, unsigned char* __restrict__ qf8,
                         float* __restrict__ q2) {
    __shared__ float s[64][65];
    int bx  = blockIdx.x;
    int b   = bx / 192;
    int rem = bx % 192;
    int hw0 = (rem & 15) * 64;
    int eg  = rem >> 4;                           // 0..11
    int e0  = eg * 64;
    const float* src = emb + (size_t)b * KD * 1024;
    unsigned int* q4 = (unsigned int*)qf8;
    #pragma unroll
    for (int i = 0; i < 16; ++i) {
        int idx = threadIdx.x + i * 256;          // 0..4095
        int ee = idx >> 6, hh = idx & 63;
        s[ee][hh] = src[(size_t)(e0 + ee) * 1024 + hw0 + hh];
    }
    __syncthreads();
    #pragma unroll
    for (int i = 0; i < 4; ++i) {
        int slot = threadIdx.x + i * 256;         // 0..1023 : (qq, e4)
        int qq = slot >> 4, e4 = slot & 15;
        float v0 = s[e4 * 4 + 0][qq], v1 = s[e4 * 4 + 1][qq];
        float v2 = s[e4 * 4 + 2][qq], v3 = s[e4 * 4 + 3][qq];
        unsigned p = f2e4m3(v0) | (f2e4m3(v1) << 8)
                   | (f2e4m3(v2) << 16) | (f2e4m3(v3) << 24);
        q4[((size_t)b * 1024 + hw0 + qq) * (KD / 4) + e0 / 4 + e4] = p;
        float part = 0.f;
        part = fmaf(v0, v0, part); part = fmaf(v1, v1, part);
        part = fmaf(v2, v2, part); part = fmaf(v3, v3, part);
        #pragma unroll
        for (int off = 1; off < 16; off <<= 1) part += __shfl_xor(part, off, 64);
        if ((threadIdx.x & 15) == 0) atomicAdd(&q2[b * 1024 + hw0 + qq], part);
    }
}

// ---- bank -> bf8 e4m3 (zero-padded) + exact fp32 b2 norms (BIGF pad) ----
__global__ void bank_prep_k(const float* __restrict__ bank, unsigned char* __restrict__ bf8,
                            float* __restrict__ b2, int N, int Npad) {
    int gid = blockIdx.x * 256 + threadIdx.x;
    int row = gid >> 6, lane = gid & 63;
    if (row >= Npad) return;
    unsigned int* b4 = (unsigned int*)bf8;
    if (row < N) {
        const float4* src = (const float4*)(bank + (size_t)row * KD);
        float s = 0.f;
        #pragma unroll
        for (int i = 0; i < KD / 256; ++i) {
            float4 v = src[lane + i * 64];
            s = fmaf(v.x, v.x, s); s = fmaf(v.y, v.y, s);
            s = fmaf(v.z, v.z, s); s = fmaf(v.w, v.w, s);
            unsigned p = f2e4m3(v.x) | (f2e4m3(v.y) << 8)
                       | (f2e4m3(v.z) << 16) | (f2e4m3(v.w) << 24);
            b4[(size_t)row * (KD / 4) + lane + i * 64] = p;
        }
        #pragma unroll
        for (int off = 32; off; off >>= 1) s += __shfl_down(s, off, 64);
        if (lane == 0) b2[row] = s;
    } else {
        #pragma unroll
        for (int i = 0; i < KD / 256; ++i) b4[(size_t)row * (KD / 4) + lane + i * 64] = 0;
        if (lane == 0) b2[row] = BIGF;
    }
}

// ---- stage one 16 KB B K-chunk (128 rows x 128 B), XOR-swizzled on global src ----
// LDS dest lane-linear (DMA requirement); swizzle pre-applied to global address.
// 256 threads: 4 x async16 each (4 VMEM ops per thread per stage).
__device__ __forceinline__ void stage_b(unsigned char* buf, const unsigned char* gB,
                                        int k0, int tid) {
    #pragma unroll
    for (int i = 0; i < 4; ++i) {                 // 1024 slots of 16 B
        int s = tid + i * 256;
        int m = s >> 3, g = s & 7;
        int G = g ^ (m & 7);
        async16(buf + s * 16, gB + (size_t)m * KD + k0 + G * 16);
    }
}

__device__ __forceinline__ i32x8 frag_read(const unsigned char* st, int base, int o0, int o1) {
    i32x4 lo = *(const i32x4*)&st[base + o0];
    i32x4 hi = *(const i32x4*)&st[base + o1];
    return __builtin_shufflevector(lo, hi, 0, 1, 2, 3, 4, 5, 6, 7);
}

// ---- main: fp8 MFMA distance GEMM + fused top-3 ----
// R5 structure, launch_bounds fixed. Evidence chain:
//  * R3 (512,2): 116 VGPR arch + ~32 AGPR, no spill, but 8-wave monolith ->
//    only 1 block/CU resident (16 waves x 150 regs > 2048 pool) -> 2
//    waves/SIMD lockstep -> latency-bound 2440cy window, 239us.
//  * R5 (256,3): allocator budget 512/3=168 total is SPLIT arch/accum when
//    AGPRs in use -> arch cap 84 (=168/2; R4 confirmed: (256,1) -> 256 =
//    512/2). af[6][2]=96 > 84 -> total spill, 443us.
//  * Fix: (256,2) -> arch cap 128 >= 116 demand, no spill. HW occupancy
//    then computes from ACTUAL usage ~150 total/wave: 3 waves/SIMD (456 <=
//    512), LDS 3 x 51.7 = 155 KB <= 160 -> 3 blocks/CU, 12 waves. The third
//    independently-barriered block fills the other two's latency holes.
// Per-wave plan unchanged (proven R3/R5): wave 32x64, mi=2 ni=4, A in regs
// af[6][2], B-only LDS 3-ring, depth-2 DMA prefetch, counted vmcnt(4),
// one raw s_barrier per kc, VMEM-free main loop.
__global__ __launch_bounds__(256, 2)
void knn_mfma_k(const unsigned char* __restrict__ qf8, const unsigned char* __restrict__ bf8,
                const float* __restrict__ b2g, float* __restrict__ cand,
                int ntiles, int Q) {
    __shared__ unsigned char bst[3][NT * KB];     // 3 x 16 KB B chunk ring
    __shared__ float b2s[5 * NT];                 // numnt <= 5 b2 tiles

    const int tid  = threadIdx.x;
    const int lane = tid & 63;
    const int quad = lane >> 4;
    const int l15  = lane & 15;
    const int wid  = tid >> 6;                    // 0..3
    const int wm   = wid & 1;                     // M half (32 rows)
    const int wn   = wid >> 1;                    // N half (64 cols)
    const int xr   = l15 & 7;

    const int bx   = blockIdx.x;
    const int xcd  = bx & 7;
    const int rr_  = bx >> 9;                     // temporal round 0..7
    const int jj   = (bx >> 3) & 63;
    const int mt   = xcd * 16 + (jj & 15);        // 0..127, 16 mts per XCD
    const int sp   = (jj >> 4) + 4 * rr_;         // 0..31
    const int Mbase = mt * MT;

    const int numnt = (ntiles - sp + NSPLIT - 1) / NSPLIT; // 4 or 5

    // prologue: b2 for this block's N tiles -> LDS (keeps main loop VMEM-free)
    for (int idx = tid; idx < numnt * NT; idx += 256) {
        int slot = idx >> 7, col = idx & 127;
        b2s[idx] = b2g[(size_t)(sp + slot * NSPLIT) * NT + col];
    }

    // prologue: A (this wave's 32 rows, full K=768) -> registers.
    // 16x16x128 A layout: row = l15, K bytes = quad*32 + [0,32).
    const unsigned char* gA = qf8 + ((size_t)Mbase + 32 * wm + l15) * KD + quad * 32;
    i32x8 af[NKC][2];
    #pragma unroll
    for (int kc = 0; kc < NKC; ++kc)
        #pragma unroll
        for (int mi = 0; mi < 2; ++mi) {
            const i32x4* p = (const i32x4*)(gA + (size_t)mi * 16 * KD + kc * KB);
            i32x4 lo = p[0];
            i32x4 hi = p[1];
            af[kc][mi] = __builtin_shufflevector(lo, hi, 0, 1, 2, 3, 4, 5, 6, 7);
        }

    float top3[24];
    #pragma unroll
    for (int i = 0; i < 24; ++i) top3[i] = BIGF;
    f32x4 acc[2][4];
    #pragma unroll
    for (int a = 0; a < 2; ++a)
        #pragma unroll
        for (int b = 0; b < 4; ++b) acc[a][b] = (f32x4){0.f, 0.f, 0.f, 0.f};

    const int o0 = ((2 * quad) ^ xr) * 16;
    const int o1 = ((2 * quad + 1) ^ xr) * 16;
    int bb[4];
    #pragma unroll
    for (int ni = 0; ni < 4; ++ni) bb[ni] = (64 * wn + 16 * ni + l15) * KB;

    __syncthreads();                              // drains all prologue mem ops

    // depth-2 prefetch: chunks 0,1 of first tile in flight (8 DMAs/thread)
    const unsigned char* gB0 = bf8 + (size_t)sp * NT * KD;
    stage_b(bst[0], gB0, 0, tid);
    stage_b(bst[1], gB0, KB, tid);

    for (int i = 0; i < numnt; ++i) {
        const unsigned char* gBc = bf8 + (size_t)(sp + i * NSPLIT) * NT * KD;
        const bool last = (i == numnt - 1);
        const unsigned char* gBn = last ? gBc
                                 : bf8 + (size_t)(sp + (i + 1) * NSPLIT) * NT * KD;
        #pragma unroll
        for (int kc = 0; kc < NKC; ++kc) {
            // invariant: chunks c, c+1 outstanding (4 DMAs each per thread)
            if (last && kc == NKC - 1) asm volatile("s_waitcnt vmcnt(0)" ::: "memory");
            else                       asm volatile("s_waitcnt vmcnt(4)" ::: "memory");
            __builtin_amdgcn_s_barrier();         // chunk c visible to all waves
            if (!(last && kc >= NKC - 2)) {       // issue chunk c+2
                if (kc < NKC - 2) stage_b(bst[(kc + 2) % 3], gBc, (kc + 2) * KB, tid);
                else              stage_b(bst[(kc + 2) % 3], gBn, (kc - 4) * KB, tid);
            }
            const unsigned char* st = bst[kc % 3];
            #pragma unroll
            for (int ni = 0; ni < 4; ++ni) {
                i32x8 bfr = frag_read(st, bb[ni], o0, o1);
                #pragma unroll
                for (int mi = 0; mi < 2; ++mi)
                    acc[mi][ni] = __builtin_amdgcn_mfma_scale_f32_16x16x128_f8f6f4(
                        af[kc][mi], bfr, acc[mi][ni], 0, 0,   // fp8 x fp8
                        0, 127, 0, 127);                      // identity E8M0 scales
            }
        }
        // epilogue: s = b2 - 2*dot (q2 added in scores_k; per-row const
        // preserves order). Overlaps the in-flight prefetch DMAs.
        const float* b2p = &b2s[i * NT + 64 * wn];
        #pragma unroll
        for (int ni = 0; ni < 4; ++ni) {
            float b2v = b2p[16 * ni + l15];
            #pragma unroll
            for (int mi = 0; mi < 2; ++mi)
                #pragma unroll
                for (int r = 0; r < 4; ++r) {
                    float s = fmaf(-2.0f, acc[mi][ni][r], b2v);
                    ins3(&top3[(mi * 4 + r) * 3], s);
                }
        }
        #pragma unroll
        for (int a = 0; a < 2; ++a)
            #pragma unroll
            for (int b = 0; b < 4; ++b) acc[a][b] = (f32x4){0.f, 0.f, 0.f, 0.f};
    }

    // merge the 16 column-partials per query row via shfl_xor butterfly
    #pragma unroll
    for (int mi = 0; mi < 2; ++mi)
        #pragma unroll
        for (int r = 0; r < 4; ++r) {
            float a0 = top3[(mi * 4 + r) * 3 + 0];
            float a1 = top3[(mi * 4 + r) * 3 + 1];
            float a2 = top3[(mi * 4 + r) * 3 + 2];
            #pragma unroll
            for (int off = 1; off < 16; off <<= 1) {
                float b0 = __shfl_xor(a0, off, 64);
                float b1 = __shfl_xor(a1, off, 64);
                float b2x = __shfl_xor(a2, off, 64);
                float t[3] = {a0, a1, a2};
                ins3(t, b0); ins3(t, b1); ins3(t, b2x);
                a0 = t[0]; a1 = t[1]; a2 = t[2];
            }
            if (l15 == 0) {
                int row = Mbase + 32 * wm + 16 * mi + 4 * quad + r;
                float* o = cand + ((size_t)(sp * 2 + wn) * Q + row) * 3;
                o[0] = a0; o[1] = a1; o[2] = a2;
            }
        }
}

// ---- merge 64 split-partials: one WAVE per query, lane = partial ----
__global__ void scores_k(const float* __restrict__ cand, const float* __restrict__ q2g,
                         float* __restrict__ scores, int Q) {
    int gid  = blockIdx.x * 256 + threadIdx.x;
    int q    = gid >> 6;
    int lane = gid & 63;
    if (q >= Q) return;
    const float* c = cand + ((size_t)lane * Q + q) * 3;
    float a0 = c[0], a1 = c[1], a2 = c[2];
    #pragma unroll
    for (int off = 1; off < 64; off <<= 1) {
        float b0 = __shfl_xor(a0, off, 64);
        float b1 = __shfl_xor(a1, off, 64);
        float b2x = __shfl_xor(a2, off, 64);
        float t[3] = {a0, a1, a2};
        ins3(t, b0); ins3(t, b1); ins3(t, b2x);
        a0 = t[0]; a1 = t[1]; a2 = t[2];
    }
    if (lane == 0) {
        float q2 = q2g[q];
        float s = (sqrtf(fmaxf(q2 + a0, 1e-12f)) +
                   sqrtf(fmaxf(q2 + a1, 1e-12f)) +
                   sqrtf(fmaxf(q2 + a2, 1e-12f))) * (1.f / 3.f);
        scores[q] = s;
    }
}

// ---- bilinear x16 upsample, half-pixel, edge clamp ----
__global__ void upsample_k(const float* __restrict__ scores, float* __restrict__ out, int total) {
    int idx = blockIdx.x * blockDim.x + threadIdx.x;
    if (idx >= total) return;
    int x = idx & 511;
    int y = (idx >> 9) & 511;
    int b = idx >> 18;
    float sx = (x + 0.5f) * (1.f / 16.f) - 0.5f;
    float sy = (y + 0.5f) * (1.f / 16.f) - 0.5f;
    int x0 = (int)floorf(sx);
    int y0 = (int)floorf(sy);
    float wx = sx - (float)x0;
    float wy = sy - (float)y0;
    int x0c = min(max(x0, 0), 31), x1c = min(max(x0 + 1, 0), 31);
    int y0c = min(max(y0, 0), 31), y1c = min(max(y0 + 1, 0), 31);
    const float* sb = scores + (size_t)b * 1024;
    float v00 = sb[y0c * 32 + x0c], v01 = sb[y0c * 32 + x1c];
    float v10 = sb[y1c * 32 + x0c], v11 = sb[y1c * 32 + x1c];
    float v0 = v00 + wx * (v01 - v00);
    float v1 = v10 + wx * (v11 - v10);
    out[idx] = v0 + wy * (v1 - v0);
}

extern "C" void kernel_launch(void* const* d_in, const int* in_sizes, int n_in,
                              void* d_out, int out_size, void* d_ws, size_t ws_size,
                              hipStream_t stream) {
    const float* emb  = (const float*)d_in[0];
    const float* bank = (const float*)d_in[1];
    const int Q      = in_sizes[0] / KD;             // 8192
    const int B      = Q / 1024;                     // 8
    const int Nbank  = in_sizes[1] / KD;             // 20000
    const int ntiles = (Nbank + NT - 1) / NT;        // 157
    const int Npad   = ntiles * NT;                  // 20096
    const int Mtiles = Q / MT;                       // 128

    // workspace layout
    unsigned char* qf8 = (unsigned char*)d_ws;                         // Q*KD bytes
    unsigned char* bf8 = qf8 + (size_t)Q * KD;                         // Npad*KD bytes
    float* fbase  = (float*)(bf8 + (size_t)Npad * KD);
    float* q2     = fbase;                                             // Q
    float* b2     = q2 + Q;                                            // Npad
    float* cand   = b2 + Npad;                                         // NSPLIT*2*Q*3
    float* scores = cand + (size_t)NSPLIT * 2 * Q * 3;                 // Q
    float* out    = (float*)d_out;

    hipMemsetAsync(q2, 0, Q * sizeof(float), stream);  // q2 accumulated via atomicAdd
    hipLaunchKernelGGL(q_prep_k, dim3(B * 192), dim3(256), 0, stream, emb, qf8, q2);
    hipLaunchKernelGGL(bank_prep_k, dim3((Npad * 64 + 255) / 256), dim3(256), 0, stream,
                       bank, bf8, b2, Nbank, Npad);
    hipLaunchKernelGGL(knn_mfma_k, dim3(Mtiles * NSPLIT), dim3(256), 0, stream,
                       qf8, bf8, b2, cand, ntiles, Q);
    hipLaunchKernelGGL(scores_k, dim3((Q * 64 + 255) / 256), dim3(256), 0, stream,
                       cand, q2, scores, Q);
    hipLaunchKernelGGL(upsample_k, dim3((out_size + 255) / 256), dim3(256), 0, stream,
                       scores, out, out_size);
}

// Round 7
// 315.421 us; speedup vs baseline: 1.7609x; 1.0822x over previous
//
#include <hip/hip_runtime.h>
#include <math.h>

#define KD     768     // embedding dim (elements = bytes in fp8)
#define MT     64      // M tile (queries) per block (4-wave blocks)
#define NT     128     // N tile (bank rows)
#define KB     128     // K bytes per mfma_scale (K=128)
#define NKC    6       // K chunks per tile (768/128)
#define NSPLIT 32      // bank splits per M tile
#define BIGF   3.0e38f

typedef __attribute__((ext_vector_type(4))) int   i32x4;
typedef __attribute__((ext_vector_type(8))) int   i32x8;
typedef __attribute__((ext_vector_type(4))) float f32x4;

// ---- software RNE float -> OCP e4m3fn (data ~N(0,1); saturation irrelevant)
__device__ __forceinline__ unsigned f2e4m3(float x) {
    unsigned u = __float_as_uint(x);
    unsigned s = (u >> 24) & 0x80u;
    float ax = __uint_as_float(u & 0x7fffffffu);
    if (ax < 0.015625f) {                       // subnormal region: step 2^-9
        int n = (int)rintf(ax * 512.0f);        // RNE, n in [0,8]
        if (n >= 8) return s | 0x08u;
        return s | (unsigned)n;
    }
    if (ax >= 464.0f) return s | 0x7Eu;         // saturate to 448
    unsigned m = __float_as_uint(ax);
    unsigned low = m & 0xFFFFFu;
    unsigned r = m >> 20;
    r += (low > 0x80000u) || (low == 0x80000u && (r & 1u));
    int ef = (int)(r >> 3) - 120;               // -127 + 7 (carry-safe)
    return s | ((unsigned)ef << 3) | (r & 7u);
}

__device__ __forceinline__ void ins3(float* t, float v) {
    float lo0 = fminf(t[0], v);
    float hi0 = fmaxf(t[0], v);
    float lo1 = fminf(t[1], hi0);
    float hi1 = fmaxf(t[1], hi0);
    float lo2 = fminf(t[2], hi1);
    t[0] = lo0; t[1] = lo1; t[2] = lo2;
}
__device__ __forceinline__ void async16(unsigned char* lds, const unsigned char* g) {
    __builtin_amdgcn_global_load_lds(
        (const __attribute__((address_space(1))) unsigned int*)g,
        (__attribute__((address_space(3))) unsigned int*)lds, 16, 0, 0);
}

// ---- emb [B][768][1024] -> qf8 [B*1024][768] e4m3 + q2 partials (atomicAdd) ----
// grid = B * 16 hw-tiles * 12 e-groups (64 e each) = 1536 blocks (6/CU).
__global__ void q_prep_k(const float* __restrict__ emb, unsigned char* __restrict__ qf8,
                         float* __restrict__ q2) {
    __shared__ float s[64][65];
    int bx  = blockIdx.x;
    int b   = bx / 192;
    int rem = bx % 192;
    int hw0 = (rem & 15) * 64;
    int eg  = rem >> 4;                           // 0..11
    int e0  = eg * 64;
    const float* src = emb + (size_t)b * KD * 1024;
    unsigned int* q4 = (unsigned int*)qf8;
    #pragma unroll
    for (int i = 0; i < 16; ++i) {
        int idx = threadIdx.x + i * 256;          // 0..4095
        int ee = idx >> 6, hh = idx & 63;
        s[ee][hh] = src[(size_t)(e0 + ee) * 1024 + hw0 + hh];
    }
    __syncthreads();
    #pragma unroll
    for (int i = 0; i < 4; ++i) {
        int slot = threadIdx.x + i * 256;         // 0..1023 : (qq, e4)
        int qq = slot >> 4, e4 = slot & 15;
        float v0 = s[e4 * 4 + 0][qq], v1 = s[e4 * 4 + 1][qq];
        float v2 = s[e4 * 4 + 2][qq], v3 = s[e4 * 4 + 3][qq];
        unsigned p = f2e4m3(v0) | (f2e4m3(v1) << 8)
                   | (f2e4m3(v2) << 16) | (f2e4m3(v3) << 24);
        q4[((size_t)b * 1024 + hw0 + qq) * (KD / 4) + e0 / 4 + e4] = p;
        float part = 0.f;
        part = fmaf(v0, v0, part); part = fmaf(v1, v1, part);
        part = fmaf(v2, v2, part); part = fmaf(v3, v3, part);
        #pragma unroll
        for (int off = 1; off < 16; off <<= 1) part += __shfl_xor(part, off, 64);
        if ((threadIdx.x & 15) == 0) atomicAdd(&q2[b * 1024 + hw0 + qq], part);
    }
}

// ---- bank -> bf8 e4m3 (zero-padded) + exact fp32 b2 norms (BIGF pad) ----
__global__ void bank_prep_k(const float* __restrict__ bank, unsigned char* __restrict__ bf8,
                            float* __restrict__ b2, int N, int Npad) {
    int gid = blockIdx.x * 256 + threadIdx.x;
    int row = gid >> 6, lane = gid & 63;
    if (row >= Npad) return;
    unsigned int* b4 = (unsigned int*)bf8;
    if (row < N) {
        const float4* src = (const float4*)(bank + (size_t)row * KD);
        float s = 0.f;
        #pragma unroll
        for (int i = 0; i < KD / 256; ++i) {
            float4 v = src[lane + i * 64];
            s = fmaf(v.x, v.x, s); s = fmaf(v.y, v.y, s);
            s = fmaf(v.z, v.z, s); s = fmaf(v.w, v.w, s);
            unsigned p = f2e4m3(v.x) | (f2e4m3(v.y) << 8)
                       | (f2e4m3(v.z) << 16) | (f2e4m3(v.w) << 24);
            b4[(size_t)row * (KD / 4) + lane + i * 64] = p;
        }
        #pragma unroll
        for (int off = 32; off; off >>= 1) s += __shfl_down(s, off, 64);
        if (lane == 0) b2[row] = s;
    } else {
        #pragma unroll
        for (int i = 0; i < KD / 256; ++i) b4[(size_t)row * (KD / 4) + lane + i * 64] = 0;
        if (lane == 0) b2[row] = BIGF;
    }
}

// ---- stage one 32 KB B window (2 K-chunks of 128 rows x 128 B), XOR-swizzled
// on global src; LDS dest lane-linear (DMA requirement). 8 async16/thread.
__device__ __forceinline__ void stage_w(unsigned char* buf, const unsigned char* gB,
                                        int k0, int tid) {
    #pragma unroll
    for (int h = 0; h < 2; ++h)
        #pragma unroll
        for (int i = 0; i < 4; ++i) {             // 1024 slots of 16 B per chunk
            int s = tid + i * 256;
            int m = s >> 3, g = s & 7;
            int G = g ^ (m & 7);
            async16(buf + h * (NT * KB) + s * 16,
                    gB + (size_t)m * KD + k0 + h * KB + G * 16);
        }
}

__device__ __forceinline__ i32x8 frag_read(const unsigned char* st, int base, int o0, int o1) {
    i32x4 lo = *(const i32x4*)&st[base + o0];
    i32x4 hi = *(const i32x4*)&st[base + o1];
    return __builtin_shufflevector(lo, hi, 0, 1, 2, 3, 4, 5, 6, 7);
}

// ---- main: fp8 MFMA distance GEMM + fused top-3 ----
// R6 + window restructure. Occupancy is HW-capped at 2 waves/SIMD for any
// total regs in (128,256] (R4/R6: steps at 64/128/256 — no 3-wave step),
// and A-in-regs (af 96) can't fit <=128, so we stop chasing occupancy and
// shrink the per-window serial chain instead. R6's window: 2370 cy for
// 553 cy of matrix work (MfmaUtil 23%) — the rest is per-kc barrier +
// vmcnt + exposed ds_read latency at only 2 waves/SIMD.
// Changes:
//  * Window = 2 kc (32 KB), double-buffered: halves barriers/waits/windows;
//    16 MFMA/wave/window (per-SIMD matrix 1106 cy of ~1400 cy window).
//  * LDS->reg B-frag pipeline: read kcA frags right after barrier (latency
//    starts ASAP), THEN issue next window's 8 DMAs (VALU overlaps latency),
//    then kcB frags (hidden under kcA's MFMAs via compiler lgkmcnt).
//  * Entry wait = vmcnt(0) on the batch issued one full window (~1400 cy)
//    earlier -> covered; only stage DMAs in the loop, so the count is exact.
// LDS: 2x32 KB + b2s = 68.1 KB -> 2 blocks/CU = 136 <= 160 KB.
// Regs: af 96 + acc 32(AGPR) + frag dbuf ~64 + top3 24 + misc -> ~220 < 256.
__global__ __launch_bounds__(256, 2)
void knn_mfma_k(const unsigned char* __restrict__ qf8, const unsigned char* __restrict__ bf8,
                const float* __restrict__ b2g, float* __restrict__ cand,
                int ntiles, int Q) {
    __shared__ unsigned char bst[2][2 * NT * KB];  // 2 x 32 KB window dbuf
    __shared__ float b2s[5 * NT];                  // numnt <= 5 b2 tiles

    const int tid  = threadIdx.x;
    const int lane = tid & 63;
    const int quad = lane >> 4;
    const int l15  = lane & 15;
    const int wid  = tid >> 6;                    // 0..3
    const int wm   = wid & 1;                     // M half (32 rows)
    const int wn   = wid >> 1;                    // N half (64 cols)
    const int xr   = l15 & 7;

    const int bx   = blockIdx.x;
    const int xcd  = bx & 7;
    const int rr_  = bx >> 9;                     // temporal round 0..7
    const int jj   = (bx >> 3) & 63;
    const int mt   = xcd * 16 + (jj & 15);        // 0..127, 16 mts per XCD
    const int sp   = (jj >> 4) + 4 * rr_;         // 0..31
    const int Mbase = mt * MT;

    const int numnt = (ntiles - sp + NSPLIT - 1) / NSPLIT; // 4 or 5

    // prologue: b2 for this block's N tiles -> LDS (keeps main loop VMEM-free)
    for (int idx = tid; idx < numnt * NT; idx += 256) {
        int slot = idx >> 7, col = idx & 127;
        b2s[idx] = b2g[(size_t)(sp + slot * NSPLIT) * NT + col];
    }

    // prologue: A (this wave's 32 rows, full K=768) -> registers.
    // 16x16x128 A layout: row = l15, K bytes = quad*32 + [0,32).
    const unsigned char* gA = qf8 + ((size_t)Mbase + 32 * wm + l15) * KD + quad * 32;
    i32x8 af[NKC][2];
    #pragma unroll
    for (int kc = 0; kc < NKC; ++kc)
        #pragma unroll
        for (int mi = 0; mi < 2; ++mi) {
            const i32x4* p = (const i32x4*)(gA + (size_t)mi * 16 * KD + kc * KB);
            i32x4 lo = p[0];
            i32x4 hi = p[1];
            af[kc][mi] = __builtin_shufflevector(lo, hi, 0, 1, 2, 3, 4, 5, 6, 7);
        }

    float top3[24];
    #pragma unroll
    for (int i = 0; i < 24; ++i) top3[i] = BIGF;
    f32x4 acc[2][4];
    #pragma unroll
    for (int a = 0; a < 2; ++a)
        #pragma unroll
        for (int b = 0; b < 4; ++b) acc[a][b] = (f32x4){0.f, 0.f, 0.f, 0.f};

    const int o0 = ((2 * quad) ^ xr) * 16;
    const int o1 = ((2 * quad + 1) ^ xr) * 16;
    int bb[4];
    #pragma unroll
    for (int ni = 0; ni < 4; ++ni) bb[ni] = (64 * wn + 16 * ni + l15) * KB;

    __syncthreads();                              // drains all prologue mem ops

    // prefetch window 0 (kc 0,1) of first tile
    const unsigned char* gB0 = bf8 + (size_t)sp * NT * KD;
    stage_w(bst[0], gB0, 0, tid);

    int pp = 0;
    for (int i = 0; i < numnt; ++i) {
        const unsigned char* gBc = bf8 + (size_t)(sp + i * NSPLIT) * NT * KD;
        const bool lastt = (i == numnt - 1);
        const unsigned char* gBn = lastt ? gBc
                                 : bf8 + (size_t)(sp + (i + 1) * NSPLIT) * NT * KD;
        #pragma unroll
        for (int w = 0; w < 3; ++w) {             // window = kc {2w, 2w+1}
            // batch for this window was issued one full window ago -> covered
            asm volatile("s_waitcnt vmcnt(0)" ::: "memory");
            __builtin_amdgcn_s_barrier();         // window resident, prior reads done
            const unsigned char* st = bst[pp];
            // kcA frags first: ds_read latency starts immediately
            i32x8 ba[4];
            #pragma unroll
            for (int ni = 0; ni < 4; ++ni) ba[ni] = frag_read(st, bb[ni], o0, o1);
            // issue next window's DMAs (VALU issue overlaps frag latency)
            if (!(lastt && w == 2)) {
                if (w < 2) stage_w(bst[pp ^ 1], gBc, (2 * w + 2) * KB, tid);
                else       stage_w(bst[pp ^ 1], gBn, 0, tid);
            }
            // kcB frags: latency hidden under kcA's MFMAs (counted lgkmcnt)
            i32x8 bbf[4];
            #pragma unroll
            for (int ni = 0; ni < 4; ++ni)
                bbf[ni] = frag_read(st + NT * KB, bb[ni], o0, o1);
            #pragma unroll
            for (int ni = 0; ni < 4; ++ni)
                #pragma unroll
                for (int mi = 0; mi < 2; ++mi)
                    acc[mi][ni] = __builtin_amdgcn_mfma_scale_f32_16x16x128_f8f6f4(
                        af[2 * w][mi], ba[ni], acc[mi][ni], 0, 0,
                        0, 127, 0, 127);          // identity E8M0 scales
            #pragma unroll
            for (int ni = 0; ni < 4; ++ni)
                #pragma unroll
                for (int mi = 0; mi < 2; ++mi)
                    acc[mi][ni] = __builtin_amdgcn_mfma_scale_f32_16x16x128_f8f6f4(
                        af[2 * w + 1][mi], bbf[ni], acc[mi][ni], 0, 0,
                        0, 127, 0, 127);
            pp ^= 1;
        }
        // epilogue: s = b2 - 2*dot (q2 added in scores_k; per-row const
        // preserves order). Overlaps the in-flight next-window DMAs.
        const float* b2p = &b2s[i * NT + 64 * wn];
        #pragma unroll
        for (int ni = 0; ni < 4; ++ni) {
            float b2v = b2p[16 * ni + l15];
            #pragma unroll
            for (int mi = 0; mi < 2; ++mi)
                #pragma unroll
                for (int r = 0; r < 4; ++r) {
                    float s = fmaf(-2.0f, acc[mi][ni][r], b2v);
                    ins3(&top3[(mi * 4 + r) * 3], s);
                }
        }
        #pragma unroll
        for (int a = 0; a < 2; ++a)
            #pragma unroll
            for (int b = 0; b < 4; ++b) acc[a][b] = (f32x4){0.f, 0.f, 0.f, 0.f};
    }

    // merge the 16 column-partials per query row via shfl_xor butterfly
    #pragma unroll
    for (int mi = 0; mi < 2; ++mi)
        #pragma unroll
        for (int r = 0; r < 4; ++r) {
            float a0 = top3[(mi * 4 + r) * 3 + 0];
            float a1 = top3[(mi * 4 + r) * 3 + 1];
            float a2 = top3[(mi * 4 + r) * 3 + 2];
            #pragma unroll
            for (int off = 1; off < 16; off <<= 1) {
                float b0 = __shfl_xor(a0, off, 64);
                float b1 = __shfl_xor(a1, off, 64);
                float b2x = __shfl_xor(a2, off, 64);
                float t[3] = {a0, a1, a2};
                ins3(t, b0); ins3(t, b1); ins3(t, b2x);
                a0 = t[0]; a1 = t[1]; a2 = t[2];
            }
            if (l15 == 0) {
                int row = Mbase + 32 * wm + 16 * mi + 4 * quad + r;
                float* o = cand + ((size_t)(sp * 2 + wn) * Q + row) * 3;
                o[0] = a0; o[1] = a1; o[2] = a2;
            }
        }
}

// ---- merge 64 split-partials: one WAVE per query, lane = partial ----
__global__ void scores_k(const float* __restrict__ cand, const float* __restrict__ q2g,
                         float* __restrict__ scores, int Q) {
    int gid  = blockIdx.x * 256 + threadIdx.x;
    int q    = gid >> 6;
    int lane = gid & 63;
    if (q >= Q) return;
    const float* c = cand + ((size_t)lane * Q + q) * 3;
    float a0 = c[0], a1 = c[1], a2 = c[2];
    #pragma unroll
    for (int off = 1; off < 64; off <<= 1) {
        float b0 = __shfl_xor(a0, off, 64);
        float b1 = __shfl_xor(a1, off, 64);
        float b2x = __shfl_xor(a2, off, 64);
        float t[3] = {a0, a1, a2};
        ins3(t, b0); ins3(t, b1); ins3(t, b2x);
        a0 = t[0]; a1 = t[1]; a2 = t[2];
    }
    if (lane == 0) {
        float q2 = q2g[q];
        float s = (sqrtf(fmaxf(q2 + a0, 1e-12f)) +
                   sqrtf(fmaxf(q2 + a1, 1e-12f)) +
                   sqrtf(fmaxf(q2 + a2, 1e-12f))) * (1.f / 3.f);
        scores[q] = s;
    }
}

// ---- bilinear x16 upsample, half-pixel, edge clamp ----
__global__ void upsample_k(const float* __restrict__ scores, float* __restrict__ out, int total) {
    int idx = blockIdx.x * blockDim.x + threadIdx.x;
    if (idx >= total) return;
    int x = idx & 511;
    int y = (idx >> 9) & 511;
    int b = idx >> 18;
    float sx = (x + 0.5f) * (1.f / 16.f) - 0.5f;
    float sy = (y + 0.5f) * (1.f / 16.f) - 0.5f;
    int x0 = (int)floorf(sx);
    int y0 = (int)floorf(sy);
    float wx = sx - (float)x0;
    float wy = sy - (float)y0;
    int x0c = min(max(x0, 0), 31), x1c = min(max(x0 + 1, 0), 31);
    int y0c = min(max(y0, 0), 31), y1c = min(max(y0 + 1, 0), 31);
    const float* sb = scores + (size_t)b * 1024;
    float v00 = sb[y0c * 32 + x0c], v01 = sb[y0c * 32 + x1c];
    float v10 = sb[y1c * 32 + x0c], v11 = sb[y1c * 32 + x1c];
    float v0 = v00 + wx * (v01 - v00);
    float v1 = v10 + wx * (v11 - v10);
    out[idx] = v0 + wy * (v1 - v0);
}

extern "C" void kernel_launch(void* const* d_in, const int* in_sizes, int n_in,
                              void* d_out, int out_size, void* d_ws, size_t ws_size,
                              hipStream_t stream) {
    const float* emb  = (const float*)d_in[0];
    const float* bank = (const float*)d_in[1];
    const int Q      = in_sizes[0] / KD;             // 8192
    const int B      = Q / 1024;                     // 8
    const int Nbank  = in_sizes[1] / KD;             // 20000
    const int ntiles = (Nbank + NT - 1) / NT;        // 157
    const int Npad   = ntiles * NT;                  // 20096
    const int Mtiles = Q / MT;                       // 128

    // workspace layout
    unsigned char* qf8 = (unsigned char*)d_ws;                         // Q*KD bytes
    unsigned char* bf8 = qf8 + (size_t)Q * KD;                         // Npad*KD bytes
    float* fbase  = (float*)(bf8 + (size_t)Npad * KD);
    float* q2     = fbase;                                             // Q
    float* b2     = q2 + Q;                                            // Npad
    float* cand   = b2 + Npad;                                         // NSPLIT*2*Q*3
    float* scores = cand + (size_t)NSPLIT * 2 * Q * 3;                 // Q
    float* out    = (float*)d_out;

    hipMemsetAsync(q2, 0, Q * sizeof(float), stream);  // q2 accumulated via atomicAdd
    hipLaunchKernelGGL(q_prep_k, dim3(B * 192), dim3(256), 0, stream, emb, qf8, q2);
    hipLaunchKernelGGL(bank_prep_k, dim3((Npad * 64 + 255) / 256), dim3(256), 0, stream,
                       bank, bf8, b2, Nbank, Npad);
    hipLaunchKernelGGL(knn_mfma_k, dim3(Mtiles * NSPLIT), dim3(256), 0, stream,
                       qf8, bf8, b2, cand, ntiles, Q);
    hipLaunchKernelGGL(scores_k, dim3((Q * 64 + 255) / 256), dim3(256), 0, stream,
                       cand, q2, scores, Q);
    hipLaunchKernelGGL(upsample_k, dim3((out_size + 255) / 256), dim3(256), 0, stream,
                       scores, out, out_size);
}